// Round 9
// baseline (1983.429 us; speedup 1.0000x reference)
//
#include <hip/hip_runtime.h>
#include <hip/hip_bf16.h>
#include <stdint.h>

// Problem constants: [T,B,D]=[4096,4,1024], H=4096. f32 inputs, f32 outputs.
// Outputs: soft [B,T] f32 at out[0..16384), hard [B,T] f32 at out[16384..32768).
#define T_STEPS 4096
#define BATCH   4
#define D_IN    1024
#define H_DIM   4096
#define M_ROWS  (T_STEPS * BATCH)

typedef __attribute__((ext_vector_type(8))) short bf16x8;
typedef __attribute__((ext_vector_type(4))) float f32x4;

__device__ __forceinline__ float b2f(unsigned short u) {
    union { unsigned int i; float f; } x; x.i = ((unsigned int)u) << 16; return x.f;
}
__device__ __forceinline__ unsigned short f2bf_rne(float f) {
    union { float f; unsigned int u; } v; v.f = f;
    return (unsigned short)((v.u + 0x7FFFu + ((v.u >> 16) & 1u)) >> 16);
}

__device__ __forceinline__ void load_lds16(const unsigned short* g, unsigned short* l) {
    __builtin_amdgcn_global_load_lds(
        (const __attribute__((address_space(1))) void*)g,
        (__attribute__((address_space(3))) void*)l, 16, 0, 0);
}

// ---------------- prep: zero logits + split X + split/transpose W (one launch) ----------------
// blocks [0,16384): split_x | [16384,18432): split_w | [18432,18560): zero logits
__global__ void __launch_bounds__(256)
prep(const float* __restrict__ hidden,
     const float* __restrict__ Wb1, const float* __restrict__ Wr1,
     unsigned short* __restrict__ Xhi, unsigned short* __restrict__ Xlo,
     unsigned short* __restrict__ WThi, unsigned short* __restrict__ WTlo,
     float* __restrict__ logits)
{
    __shared__ float tile[64][65];
    const int bid = blockIdx.x;
    const int t = threadIdx.x;

    if (bid < 16384) {
        // split hidden f32 -> (hi, lo) bf16, same layout; 256 float4 per block
        int i = bid * 256 + t;
        float4 x = ((const float4*)hidden)[i];
        ushort4 h, l;
        h.x = f2bf_rne(x.x); l.x = f2bf_rne(x.x - b2f(h.x));
        h.y = f2bf_rne(x.y); l.y = f2bf_rne(x.y - b2f(h.y));
        h.z = f2bf_rne(x.z); l.z = f2bf_rne(x.z - b2f(h.z));
        h.w = f2bf_rne(x.w); l.w = f2bf_rne(x.w - b2f(h.w));
        ((ushort4*)Xhi)[i] = h;
        ((ushort4*)Xlo)[i] = l;
    } else if (bid < 18432) {
        // transpose+split W [D][H] -> WT [H][D] for both matrices
        int wb  = bid - 16384;
        int z   = wb >> 10;                   // 0=boundary, 1=reset
        int rem = wb & 1023;
        int bx  = (rem & 63) * 64;            // H direction
        int by  = (rem >> 6) * 64;            // D direction
        const float* src = z ? Wr1 : Wb1;
        const size_t moff = (size_t)z * H_DIM * D_IN;
        const int c4 = (t & 15) * 4;
        const int r0 = (t >> 4) * 4;
#pragma unroll
        for (int rr = 0; rr < 4; ++rr) {
            int r = r0 + rr;
            float4 v = *(const float4*)(src + (size_t)(by + r) * H_DIM + bx + c4);
            tile[r][c4 + 0] = v.x; tile[r][c4 + 1] = v.y;
            tile[r][c4 + 2] = v.z; tile[r][c4 + 3] = v.w;
        }
        __syncthreads();
#pragma unroll
        for (int rr = 0; rr < 4; ++rr) {
            int c = r0 + rr;
            ushort4 h, l;
            float f0 = tile[c4 + 0][c], f1 = tile[c4 + 1][c];
            float f2 = tile[c4 + 2][c], f3 = tile[c4 + 3][c];
            h.x = f2bf_rne(f0); l.x = f2bf_rne(f0 - b2f(h.x));
            h.y = f2bf_rne(f1); l.y = f2bf_rne(f1 - b2f(h.y));
            h.z = f2bf_rne(f2); l.z = f2bf_rne(f2 - b2f(h.z));
            h.w = f2bf_rne(f3); l.w = f2bf_rne(f3 - b2f(h.w));
            size_t o = moff + (size_t)(bx + c) * D_IN + by + c4;
            *(ushort4*)(WThi + o) = h;
            *(ushort4*)(WTlo + o) = l;
        }
    } else {
        int i = (bid - 18432) * 256 + t;      // 128 blocks x 256 = 32768 = 2*M_ROWS
        logits[i] = 0.f;
    }
}

// ------------- fused split-f32 GEMM + relu + (.)@W2 reduction -------------
// acc = Xhi.WThi + Xlo.WThi (phase 0, shared B staging) + Xhi.WTlo (phase 1)
// A-operand: DIRECT from global to registers (no LDS round trip).
// B-operand: LDS-staged 128x64, XOR-swizzled (chunk c of row r at slot c^(r&7)) -> 0 conflicts.
// 128x128 tile, BK=64, 4 waves x (64x64), 16x16x32 bf16 MFMA.
__global__ void __launch_bounds__(256)
gemm_fused2(const unsigned short* __restrict__ Xhi, const unsigned short* __restrict__ Xlo,
            const unsigned short* __restrict__ WThi, const unsigned short* __restrict__ WTlo,
            const float* __restrict__ b1b, const float* __restrict__ b1r,
            const float* __restrict__ w2b, const float* __restrict__ w2r,
            float* __restrict__ logits)              // [2][B][T] f32, atomically accumulated
{
    __shared__ __align__(16) unsigned short Blds[128 * 64];   // 16 KB

    const int t    = threadIdx.x;
    const int wave = t >> 6;
    const int lane = t & 63;
    const int quad = lane >> 4;
    const int lr   = lane & 15;
    const int w_m  = (wave & 1) * 64;
    const int w_n  = (wave >> 1) * 64;

    const int mat = blockIdx.z;
    const int n0  = blockIdx.x * 128;
    const int m0  = blockIdx.y * 128;

    const unsigned short* Ahi = Xhi + (size_t)m0 * D_IN;
    const unsigned short* Alo = Xlo + (size_t)m0 * D_IN;
    const size_t boff = (size_t)mat * H_DIM * D_IN + (size_t)n0 * D_IN;
    const unsigned short* B0 = WThi + boff;
    const unsigned short* B1 = WTlo + boff;
    const float* b1 = mat ? b1r : b1b;
    const float* w2 = mat ? w2r : w2b;
    float* out = logits + mat * M_ROWS;

    // per-lane A row offsets (frag layout: A[m=lr][k=quad*8+j], kc selects 32-window)
    int arow[4];
#pragma unroll
    for (int i = 0; i < 4; ++i) arow[i] = (w_m + i * 16 + lr) * D_IN + quad * 8;

    // B staging: thread t stages chunks jj*256+t; row = jj*32+(t>>3), phys chunk t&7,
    // swizzled source chunk (t&7)^(row&7)
    const int srow = t >> 3;
    const int scol = (((t & 7) ^ (srow & 7)) * 8);

    f32x4 acc[4][4] = {};

    // ---- phase 0: B = WThi; acc += Xhi.B + Xlo.B ----
#pragma unroll 1
    for (int kt = 0; kt < D_IN / 64; ++kt) {
        const int k0 = kt * 64;
#pragma unroll
        for (int jj = 0; jj < 4; ++jj)
            load_lds16(B0 + (size_t)(jj * 32 + srow) * D_IN + k0 + scol, Blds + jj * 2048 + wave * 512);
        bf16x8 ah[8], al[8];
#pragma unroll
        for (int kc = 0; kc < 2; ++kc)
#pragma unroll
            for (int i = 0; i < 4; ++i) {
                ah[kc * 4 + i] = *(const bf16x8*)(Ahi + arow[i] + k0 + kc * 32);
                al[kc * 4 + i] = *(const bf16x8*)(Alo + arow[i] + k0 + kc * 32);
            }
        __syncthreads();
#pragma unroll
        for (int kc = 0; kc < 2; ++kc) {
            bf16x8 bfv[4];
            const int pc = ((kc * 4 + quad) ^ (lr & 7)) * 8;
#pragma unroll
            for (int j = 0; j < 4; ++j)
                bfv[j] = *(const bf16x8*)(Blds + (w_n + j * 16 + lr) * 64 + pc);
#pragma unroll
            for (int i = 0; i < 4; ++i)
#pragma unroll
                for (int j = 0; j < 4; ++j)
                    acc[i][j] = __builtin_amdgcn_mfma_f32_16x16x32_bf16(ah[kc * 4 + i], bfv[j], acc[i][j], 0, 0, 0);
#pragma unroll
            for (int i = 0; i < 4; ++i)
#pragma unroll
                for (int j = 0; j < 4; ++j)
                    acc[i][j] = __builtin_amdgcn_mfma_f32_16x16x32_bf16(al[kc * 4 + i], bfv[j], acc[i][j], 0, 0, 0);
        }
        __syncthreads();
    }

    // ---- phase 1: B = WTlo; acc += Xhi.B ----
#pragma unroll 1
    for (int kt = 0; kt < D_IN / 64; ++kt) {
        const int k0 = kt * 64;
#pragma unroll
        for (int jj = 0; jj < 4; ++jj)
            load_lds16(B1 + (size_t)(jj * 32 + srow) * D_IN + k0 + scol, Blds + jj * 2048 + wave * 512);
        bf16x8 ah[8];
#pragma unroll
        for (int kc = 0; kc < 2; ++kc)
#pragma unroll
            for (int i = 0; i < 4; ++i)
                ah[kc * 4 + i] = *(const bf16x8*)(Ahi + arow[i] + k0 + kc * 32);
        __syncthreads();
#pragma unroll
        for (int kc = 0; kc < 2; ++kc) {
            bf16x8 bfv[4];
            const int pc = ((kc * 4 + quad) ^ (lr & 7)) * 8;
#pragma unroll
            for (int j = 0; j < 4; ++j)
                bfv[j] = *(const bf16x8*)(Blds + (w_n + j * 16 + lr) * 64 + pc);
#pragma unroll
            for (int i = 0; i < 4; ++i)
#pragma unroll
                for (int j = 0; j < 4; ++j)
                    acc[i][j] = __builtin_amdgcn_mfma_f32_16x16x32_bf16(ah[kc * 4 + i], bfv[j], acc[i][j], 0, 0, 0);
        }
        __syncthreads();
    }

    // epilogue: relu(C + b1)*w2, reduce over this tile's n, accumulate to logits
    float b1v[4], w2v[4];
#pragma unroll
    for (int j = 0; j < 4; ++j) {
        int n = n0 + w_n + j * 16 + lr;              // C/D col = lane&15
        b1v[j] = b1[n];
        w2v[j] = w2[n];
    }
#pragma unroll
    for (int i = 0; i < 4; ++i) {
#pragma unroll
        for (int r = 0; r < 4; ++r) {
            float s = 0.f;
#pragma unroll
            for (int j = 0; j < 4; ++j) {
                float h = acc[i][j][r] + b1v[j];
                s += fmaxf(h, 0.f) * w2v[j];
            }
            s += __shfl_xor(s, 1, 64);
            s += __shfl_xor(s, 2, 64);
            s += __shfl_xor(s, 4, 64);
            s += __shfl_xor(s, 8, 64);
            if (lr == 0) {
                int m = m0 + w_m + i * 16 + quad * 4 + r;   // C/D row = quad*4 + reg
                atomicAdd(&out[(m & (BATCH - 1)) * T_STEPS + (m >> 2)], s);  // -> [b][t]
            }
        }
    }
}

// ------------- finish: soft output (blocks 0..63) + serial LIF scan (block 64) -------------
__global__ void __launch_bounds__(256)
finish(const float* __restrict__ logits,
       const float* __restrict__ bb2p, const float* __restrict__ br2p,
       float* __restrict__ out)
{
    if (blockIdx.x < 64) {
        int i = blockIdx.x * 256 + threadIdx.x;
        out[i] = logits[i] + bb2p[0];                // soft = boundary logits [b][t] + bb2
        return;
    }
    int b = threadIdx.x;
    if (b >= BATCH) return;
    const float bb2 = bb2p[0];
    const float br2 = br2p[0];
    const float* xb = logits + b * T_STEPS;          // boundary logits, [b][t]
    const float* xr = logits + M_ROWS + b * T_STEPS; // reset logits
    float* hb = out + M_ROWS + b * T_STEPS;
    float v = 0.f;
    for (int t0 = 0; t0 < T_STEPS; t0 += 4) {
        float4 xv = *(const float4*)(xb + t0);
        float4 rv = *(const float4*)(xr + t0);
#pragma unroll
        for (int u = 0; u < 4; ++u) {
            float x  = (u == 0 ? xv.x : u == 1 ? xv.y : u == 2 ? xv.z : xv.w) + bb2;
            float rl = (u == 0 ? rv.x : u == 1 ? rv.y : u == 2 ? rv.z : rv.w) + br2;
            v = v + (x - v) * 0.5f;                  // v += (x - v)/TAU, TAU=2 (exact)
            bool spike = (v >= 1.0f);                // heaviside(v - V_TH)
            hb[t0 + u] = spike ? 1.0f : 0.0f;
            v = (spike || (rl > 0.f)) ? 0.f : v;     // hard reset on spike or forced mask
        }
    }
}

extern "C" void kernel_launch(void* const* d_in, const int* in_sizes, int n_in,
                              void* d_out, int out_size, void* d_ws, size_t ws_size,
                              hipStream_t stream) {
    // dict order (confirmed): hidden, Wb1, bb1, Wb2, bb2, Wr1, br1, Wr2, br2
    const float* hidden = (const float*)d_in[0];   // [T,B,D] f32
    const float* Wb1    = (const float*)d_in[1];   // [D,H]
    const float* bb1    = (const float*)d_in[2];   // [H]
    const float* Wb2    = (const float*)d_in[3];   // [H,1]
    const float* bb2    = (const float*)d_in[4];   // [1]
    const float* Wr1    = (const float*)d_in[5];
    const float* br1    = (const float*)d_in[6];
    const float* Wr2    = (const float*)d_in[7];
    const float* br2    = (const float*)d_in[8];
    float* out = (float*)d_out;                    // f32: [soft B*T][hard B*T]

    // ws layout (96.13 MB): Xhi 32MB | Xlo 32MB | WThi 16MB | WTlo 16MB | logits 128KB
    unsigned short* Xhi  = (unsigned short*)d_ws;
    unsigned short* Xlo  = Xhi  + (size_t)M_ROWS * D_IN;
    unsigned short* WThi = Xlo  + (size_t)M_ROWS * D_IN;
    unsigned short* WTlo = WThi + (size_t)2 * H_DIM * D_IN;
    float* logits = (float*)(WTlo + (size_t)2 * H_DIM * D_IN);

    prep<<<dim3(18560), 256, 0, stream>>>(hidden, Wb1, Wr1, Xhi, Xlo, WThi, WTlo, logits);
    gemm_fused2<<<dim3(H_DIM / 128, M_ROWS / 128, 2), 256, 0, stream>>>(
        Xhi, Xlo, WThi, WTlo, bb1, br1, Wb2, Wr2, logits);
    finish<<<dim3(65), 256, 0, stream>>>(logits, bb2, br2, out);
}

// Round 10
// 1445.774 us; speedup vs baseline: 1.3719x; 1.3719x over previous
//
#include <hip/hip_runtime.h>
#include <hip/hip_bf16.h>
#include <stdint.h>

// Problem constants: [T,B,D]=[4096,4,1024], H=4096. f32 inputs, f32 outputs.
// Outputs: soft [B,T] f32 at out[0..16384), hard [B,T] f32 at out[16384..32768).
#define T_STEPS 4096
#define BATCH   4
#define D_IN    1024
#define H_DIM   4096
#define M_ROWS  (T_STEPS * BATCH)

typedef __attribute__((ext_vector_type(8))) short bf16x8;
typedef __attribute__((ext_vector_type(4))) float f32x4;

__device__ __forceinline__ float b2f(unsigned short u) {
    union { unsigned int i; float f; } x; x.i = ((unsigned int)u) << 16; return x.f;
}
__device__ __forceinline__ unsigned short f2bf_rne(float f) {
    union { float f; unsigned int u; } v; v.f = f;
    return (unsigned short)((v.u + 0x7FFFu + ((v.u >> 16) & 1u)) >> 16);
}

__device__ __forceinline__ void load_lds16(const unsigned short* g, unsigned short* l) {
    __builtin_amdgcn_global_load_lds(
        (const __attribute__((address_space(1))) void*)g,
        (__attribute__((address_space(3))) void*)l, 16, 0, 0);
}

// ---------------- prep: zero logits + split X + split/transpose W (one launch) ----------------
// blocks [0,16384): split_x | [16384,18432): split_w | [18432,18560): zero logits
__global__ void __launch_bounds__(256)
prep(const float* __restrict__ hidden,
     const float* __restrict__ Wb1, const float* __restrict__ Wr1,
     unsigned short* __restrict__ Xhi, unsigned short* __restrict__ Xlo,
     unsigned short* __restrict__ WThi, unsigned short* __restrict__ WTlo,
     float* __restrict__ logits)
{
    __shared__ float tile[64][65];
    const int bid = blockIdx.x;
    const int t = threadIdx.x;

    if (bid < 16384) {
        // split hidden f32 -> (hi, lo) bf16, same layout; 256 float4 per block
        int i = bid * 256 + t;
        float4 x = ((const float4*)hidden)[i];
        ushort4 h, l;
        h.x = f2bf_rne(x.x); l.x = f2bf_rne(x.x - b2f(h.x));
        h.y = f2bf_rne(x.y); l.y = f2bf_rne(x.y - b2f(h.y));
        h.z = f2bf_rne(x.z); l.z = f2bf_rne(x.z - b2f(h.z));
        h.w = f2bf_rne(x.w); l.w = f2bf_rne(x.w - b2f(h.w));
        ((ushort4*)Xhi)[i] = h;
        ((ushort4*)Xlo)[i] = l;
    } else if (bid < 18432) {
        // transpose+split W [D][H] -> WT [H][D] for both matrices
        int wb  = bid - 16384;
        int z   = wb >> 10;                   // 0=boundary, 1=reset
        int rem = wb & 1023;
        int bx  = (rem & 63) * 64;            // H direction
        int by  = (rem >> 6) * 64;            // D direction
        const float* src = z ? Wr1 : Wb1;
        const size_t moff = (size_t)z * H_DIM * D_IN;
        const int c4 = (t & 15) * 4;
        const int r0 = (t >> 4) * 4;
#pragma unroll
        for (int rr = 0; rr < 4; ++rr) {
            int r = r0 + rr;
            float4 v = *(const float4*)(src + (size_t)(by + r) * H_DIM + bx + c4);
            tile[r][c4 + 0] = v.x; tile[r][c4 + 1] = v.y;
            tile[r][c4 + 2] = v.z; tile[r][c4 + 3] = v.w;
        }
        __syncthreads();
#pragma unroll
        for (int rr = 0; rr < 4; ++rr) {
            int c = r0 + rr;
            ushort4 h, l;
            float f0 = tile[c4 + 0][c], f1 = tile[c4 + 1][c];
            float f2 = tile[c4 + 2][c], f3 = tile[c4 + 3][c];
            h.x = f2bf_rne(f0); l.x = f2bf_rne(f0 - b2f(h.x));
            h.y = f2bf_rne(f1); l.y = f2bf_rne(f1 - b2f(h.y));
            h.z = f2bf_rne(f2); l.z = f2bf_rne(f2 - b2f(h.z));
            h.w = f2bf_rne(f3); l.w = f2bf_rne(f3 - b2f(h.w));
            size_t o = moff + (size_t)(bx + c) * D_IN + by + c4;
            *(ushort4*)(WThi + o) = h;
            *(ushort4*)(WTlo + o) = l;
        }
    } else {
        int i = (bid - 18432) * 256 + t;      // 128 blocks x 256 = 32768 = 2*M_ROWS
        logits[i] = 0.f;
    }
}

// ------------- fused split-f32 GEMM + relu + (.)@W2 reduction -------------
// 3 K-phases: Xhi.WThi + Xhi.WTlo + Xlo.WThi ~= f32 X.W (residual ~2^-18 rel)
// Block tile 128m x 256n, BK=64, 4 waves, wave tile 64m x 128n (4x8 frags, 16x16x32 bf16).
// Both operands LDS-staged (r9 lesson: never fetch MFMA frag patterns scattered from global).
// XOR swizzle: row r stores global 16B-chunk c at slot c^(r&7) -> 0 bank conflicts (r7-proven).
__global__ void __launch_bounds__(256)
gemm_fused3(const unsigned short* __restrict__ Xhi, const unsigned short* __restrict__ Xlo,
            const unsigned short* __restrict__ WThi, const unsigned short* __restrict__ WTlo,
            const float* __restrict__ b1b, const float* __restrict__ b1r,
            const float* __restrict__ w2b, const float* __restrict__ w2r,
            float* __restrict__ logits)              // [2][B][T] f32, atomically accumulated
{
    __shared__ __align__(16) unsigned short Alds[128 * 64];   // 16 KB
    __shared__ __align__(16) unsigned short Blds[256 * 64];   // 32 KB

    const int t    = threadIdx.x;
    const int wave = t >> 6;
    const int lane = t & 63;
    const int quad = lane >> 4;
    const int lr   = lane & 15;
    const int w_m  = (wave & 1) * 64;
    const int w_n  = (wave >> 1) * 128;

    const int mat = blockIdx.z;
    const int n0  = blockIdx.x * 256;
    const int m0  = blockIdx.y * 128;

    const size_t aoff = (size_t)m0 * D_IN;
    const size_t boff = (size_t)mat * H_DIM * D_IN + (size_t)n0 * D_IN;
    const unsigned short* Aph[3] = { Xhi + aoff, Xhi + aoff, Xlo + aoff };
    const unsigned short* Bph[3] = { WThi + boff, WTlo + boff, WThi + boff };
    const float* b1 = mat ? b1r : b1b;
    const float* w2 = mat ? w2r : w2b;
    float* out = logits + mat * M_ROWS;

    // staging: thread t covers phys chunk (t&7) of rows {g*32 + (t>>3)}; XOR-swizzled source
    const int srow = t >> 3;
    const int scol = (((t & 7) ^ (srow & 7)) * 8);

    f32x4 acc[4][8] = {};

#pragma unroll 1
    for (int ph = 0; ph < 3; ++ph) {
        const unsigned short* A = Aph[ph];
        const unsigned short* B = Bph[ph];
#pragma unroll 1
        for (int kt = 0; kt < D_IN / 64; ++kt) {
            const int k0 = kt * 64;
#pragma unroll
            for (int i = 0; i < 4; ++i)
                load_lds16(A + (size_t)(i * 32 + srow) * D_IN + k0 + scol, Alds + i * 2048 + wave * 512);
#pragma unroll
            for (int jj = 0; jj < 8; ++jj)
                load_lds16(B + (size_t)(jj * 32 + srow) * D_IN + k0 + scol, Blds + jj * 2048 + wave * 512);
            __syncthreads();
#pragma unroll
            for (int kc = 0; kc < 2; ++kc) {
                const int pc = ((kc * 4 + quad) ^ (lr & 7)) * 8;   // swizzled physical chunk
                bf16x8 af[4], bfv[8];
#pragma unroll
                for (int i = 0; i < 4; ++i)
                    af[i] = *(const bf16x8*)(Alds + (w_m + i * 16 + lr) * 64 + pc);
#pragma unroll
                for (int j = 0; j < 8; ++j)
                    bfv[j] = *(const bf16x8*)(Blds + (w_n + j * 16 + lr) * 64 + pc);
#pragma unroll
                for (int i = 0; i < 4; ++i)
#pragma unroll
                    for (int j = 0; j < 8; ++j)
                        acc[i][j] = __builtin_amdgcn_mfma_f32_16x16x32_bf16(af[i], bfv[j], acc[i][j], 0, 0, 0);
            }
            __syncthreads();
        }
    }

    // epilogue: relu(C + b1)*w2, reduce over this tile's n, accumulate to logits
    float b1v[8], w2v[8];
#pragma unroll
    for (int j = 0; j < 8; ++j) {
        int n = n0 + w_n + j * 16 + lr;              // C/D col = lane&15
        b1v[j] = b1[n];
        w2v[j] = w2[n];
    }
#pragma unroll
    for (int i = 0; i < 4; ++i) {
#pragma unroll
        for (int r = 0; r < 4; ++r) {
            float s = 0.f;
#pragma unroll
            for (int j = 0; j < 8; ++j) {
                float h = acc[i][j][r] + b1v[j];
                s += fmaxf(h, 0.f) * w2v[j];
            }
            s += __shfl_xor(s, 1, 64);
            s += __shfl_xor(s, 2, 64);
            s += __shfl_xor(s, 4, 64);
            s += __shfl_xor(s, 8, 64);
            if (lr == 0) {
                int m = m0 + w_m + i * 16 + quad * 4 + r;   // C/D row = quad*4 + reg
                atomicAdd(&out[(m & (BATCH - 1)) * T_STEPS + (m >> 2)], s);  // -> [b][t]
            }
        }
    }
}

// ------------- finish: soft output (blocks 0..63) + serial LIF scan (block 64) -------------
__global__ void __launch_bounds__(256)
finish(const float* __restrict__ logits,
       const float* __restrict__ bb2p, const float* __restrict__ br2p,
       float* __restrict__ out)
{
    if (blockIdx.x < 64) {
        int i = blockIdx.x * 256 + threadIdx.x;
        out[i] = logits[i] + bb2p[0];                // soft = boundary logits [b][t] + bb2
        return;
    }
    int b = threadIdx.x;
    if (b >= BATCH) return;
    const float bb2 = bb2p[0];
    const float br2 = br2p[0];
    const float* xb = logits + b * T_STEPS;          // boundary logits, [b][t]
    const float* xr = logits + M_ROWS + b * T_STEPS; // reset logits
    float* hb = out + M_ROWS + b * T_STEPS;
    float v = 0.f;
    for (int t0 = 0; t0 < T_STEPS; t0 += 4) {
        float4 xv = *(const float4*)(xb + t0);
        float4 rv = *(const float4*)(xr + t0);
#pragma unroll
        for (int u = 0; u < 4; ++u) {
            float x  = (u == 0 ? xv.x : u == 1 ? xv.y : u == 2 ? xv.z : xv.w) + bb2;
            float rl = (u == 0 ? rv.x : u == 1 ? rv.y : u == 2 ? rv.z : rv.w) + br2;
            v = v + (x - v) * 0.5f;                  // v += (x - v)/TAU, TAU=2 (exact)
            bool spike = (v >= 1.0f);                // heaviside(v - V_TH)
            hb[t0 + u] = spike ? 1.0f : 0.0f;
            v = (spike || (rl > 0.f)) ? 0.f : v;     // hard reset on spike or forced mask
        }
    }
}

extern "C" void kernel_launch(void* const* d_in, const int* in_sizes, int n_in,
                              void* d_out, int out_size, void* d_ws, size_t ws_size,
                              hipStream_t stream) {
    // dict order (confirmed): hidden, Wb1, bb1, Wb2, bb2, Wr1, br1, Wr2, br2
    const float* hidden = (const float*)d_in[0];   // [T,B,D] f32
    const float* Wb1    = (const float*)d_in[1];   // [D,H]
    const float* bb1    = (const float*)d_in[2];   // [H]
    const float* Wb2    = (const float*)d_in[3];   // [H,1]
    const float* bb2    = (const float*)d_in[4];   // [1]
    const float* Wr1    = (const float*)d_in[5];
    const float* br1    = (const float*)d_in[6];
    const float* Wr2    = (const float*)d_in[7];
    const float* br2    = (const float*)d_in[8];
    float* out = (float*)d_out;                    // f32: [soft B*T][hard B*T]

    // ws layout (96.13 MB): Xhi 32MB | Xlo 32MB | WThi 16MB | WTlo 16MB | logits 128KB
    unsigned short* Xhi  = (unsigned short*)d_ws;
    unsigned short* Xlo  = Xhi  + (size_t)M_ROWS * D_IN;
    unsigned short* WThi = Xlo  + (size_t)M_ROWS * D_IN;
    unsigned short* WTlo = WThi + (size_t)2 * H_DIM * D_IN;
    float* logits = (float*)(WTlo + (size_t)2 * H_DIM * D_IN);

    prep<<<dim3(18560), 256, 0, stream>>>(hidden, Wb1, Wr1, Xhi, Xlo, WThi, WTlo, logits);
    gemm_fused3<<<dim3(H_DIM / 256, M_ROWS / 128, 2), 256, 0, stream>>>(
        Xhi, Xlo, WThi, WTlo, bb1, br1, Wb2, Wr2, logits);
    finish<<<dim3(65), 256, 0, stream>>>(logits, bb2, br2, out);
}

// Round 11
// 987.113 us; speedup vs baseline: 2.0093x; 1.4646x over previous
//
#include <hip/hip_runtime.h>
#include <hip/hip_bf16.h>
#include <stdint.h>

// Problem constants: [T,B,D]=[4096,4,1024], H=4096. f32 inputs, f32 outputs.
// Outputs: soft [B,T] f32 at out[0..16384), hard [B,T] f32 at out[16384..32768).
#define T_STEPS 4096
#define BATCH   4
#define D_IN    1024
#define H_DIM   4096
#define M_ROWS  (T_STEPS * BATCH)

typedef __attribute__((ext_vector_type(8))) short bf16x8;
typedef __attribute__((ext_vector_type(4))) float f32x4;

__device__ __forceinline__ float b2f(unsigned short u) {
    union { unsigned int i; float f; } x; x.i = ((unsigned int)u) << 16; return x.f;
}
__device__ __forceinline__ unsigned short f2bf_rne(float f) {
    union { float f; unsigned int u; } v; v.f = f;
    return (unsigned short)((v.u + 0x7FFFu + ((v.u >> 16) & 1u)) >> 16);
}

__device__ __forceinline__ void load_lds16(const unsigned short* g, unsigned short* l) {
    __builtin_amdgcn_global_load_lds(
        (const __attribute__((address_space(1))) void*)g,
        (__attribute__((address_space(3))) void*)l, 16, 0, 0);
}

// ---------------- prep: zero logits + split X + split/transpose W (one launch) ----------------
// blocks [0,16384): split_x | [16384,18432): split_w | [18432,18560): zero logits
__global__ void __launch_bounds__(256)
prep(const float* __restrict__ hidden,
     const float* __restrict__ Wb1, const float* __restrict__ Wr1,
     unsigned short* __restrict__ Xhi, unsigned short* __restrict__ Xlo,
     unsigned short* __restrict__ WThi, unsigned short* __restrict__ WTlo,
     float* __restrict__ logits)
{
    __shared__ float tile[64][65];
    const int bid = blockIdx.x;
    const int t = threadIdx.x;

    if (bid < 16384) {
        // split hidden f32 -> (hi, lo) bf16, same layout; 256 float4 per block
        int i = bid * 256 + t;
        float4 x = ((const float4*)hidden)[i];
        ushort4 h, l;
        h.x = f2bf_rne(x.x); l.x = f2bf_rne(x.x - b2f(h.x));
        h.y = f2bf_rne(x.y); l.y = f2bf_rne(x.y - b2f(h.y));
        h.z = f2bf_rne(x.z); l.z = f2bf_rne(x.z - b2f(h.z));
        h.w = f2bf_rne(x.w); l.w = f2bf_rne(x.w - b2f(h.w));
        ((ushort4*)Xhi)[i] = h;
        ((ushort4*)Xlo)[i] = l;
    } else if (bid < 18432) {
        // transpose+split W [D][H] -> WT [H][D] for both matrices
        int wb  = bid - 16384;
        int z   = wb >> 10;                   // 0=boundary, 1=reset
        int rem = wb & 1023;
        int bx  = (rem & 63) * 64;            // H direction
        int by  = (rem >> 6) * 64;            // D direction
        const float* src = z ? Wr1 : Wb1;
        const size_t moff = (size_t)z * H_DIM * D_IN;
        const int c4 = (t & 15) * 4;
        const int r0 = (t >> 4) * 4;
#pragma unroll
        for (int rr = 0; rr < 4; ++rr) {
            int r = r0 + rr;
            float4 v = *(const float4*)(src + (size_t)(by + r) * H_DIM + bx + c4);
            tile[r][c4 + 0] = v.x; tile[r][c4 + 1] = v.y;
            tile[r][c4 + 2] = v.z; tile[r][c4 + 3] = v.w;
        }
        __syncthreads();
#pragma unroll
        for (int rr = 0; rr < 4; ++rr) {
            int c = r0 + rr;
            ushort4 h, l;
            float f0 = tile[c4 + 0][c], f1 = tile[c4 + 1][c];
            float f2 = tile[c4 + 2][c], f3 = tile[c4 + 3][c];
            h.x = f2bf_rne(f0); l.x = f2bf_rne(f0 - b2f(h.x));
            h.y = f2bf_rne(f1); l.y = f2bf_rne(f1 - b2f(h.y));
            h.z = f2bf_rne(f2); l.z = f2bf_rne(f2 - b2f(h.z));
            h.w = f2bf_rne(f3); l.w = f2bf_rne(f3 - b2f(h.w));
            size_t o = moff + (size_t)(bx + c) * D_IN + by + c4;
            *(ushort4*)(WThi + o) = h;
            *(ushort4*)(WTlo + o) = l;
        }
    } else {
        int i = (bid - 18432) * 256 + t;      // 128 blocks x 256 = 32768 = 2*M_ROWS
        logits[i] = 0.f;
    }
}

// ------------- fused split-f32 GEMM + relu + (.)@W2 reduction -------------
// 3 K-phases: Xhi.WThi + Xhi.WTlo + Xlo.WThi ~= f32 X.W (residual ~2^-18 rel)
// Block tile 128m x 256n, BK=64, 4 waves, wave tile 64m x 128n (4x8 frags, 16x16x32 bf16).
// __launch_bounds__(256, 2): acc = 128 AGPRs; cap VGPRs so AGPR+VGPR <= 256
// -> 2 waves/SIMD (r10 had 268 unified regs -> 1 wave/SIMD -> no MFMA/LDS overlap).
// XOR swizzle: row r stores global 16B-chunk c at slot c^(r&7) -> 0 bank conflicts (r7-proven).
__global__ void __launch_bounds__(256, 2)
gemm_fused3(const unsigned short* __restrict__ Xhi, const unsigned short* __restrict__ Xlo,
            const unsigned short* __restrict__ WThi, const unsigned short* __restrict__ WTlo,
            const float* __restrict__ b1b, const float* __restrict__ b1r,
            const float* __restrict__ w2b, const float* __restrict__ w2r,
            float* __restrict__ logits)              // [2][B][T] f32, atomically accumulated
{
    __shared__ __align__(16) unsigned short Alds[128 * 64];   // 16 KB
    __shared__ __align__(16) unsigned short Blds[256 * 64];   // 32 KB

    const int t    = threadIdx.x;
    const int wave = t >> 6;
    const int lane = t & 63;
    const int quad = lane >> 4;
    const int lr   = lane & 15;
    const int w_m  = (wave & 1) * 64;
    const int w_n  = (wave >> 1) * 128;

    const int mat = blockIdx.z;
    const int n0  = blockIdx.x * 256;
    const int m0  = blockIdx.y * 128;

    const size_t aoff = (size_t)m0 * D_IN;
    const size_t boff = (size_t)mat * H_DIM * D_IN + (size_t)n0 * D_IN;
    const unsigned short* Aph[3] = { Xhi + aoff, Xhi + aoff, Xlo + aoff };
    const unsigned short* Bph[3] = { WThi + boff, WTlo + boff, WThi + boff };
    const float* b1 = mat ? b1r : b1b;
    const float* w2 = mat ? w2r : w2b;
    float* out = logits + mat * M_ROWS;

    // staging: thread t covers phys chunk (t&7) of rows {g*32 + (t>>3)}; XOR-swizzled source
    const int srow = t >> 3;
    const int scol = (((t & 7) ^ (srow & 7)) * 8);

    f32x4 acc[4][8] = {};

#pragma unroll 1
    for (int ph = 0; ph < 3; ++ph) {
        const unsigned short* A = Aph[ph];
        const unsigned short* B = Bph[ph];
#pragma unroll 1
        for (int kt = 0; kt < D_IN / 64; ++kt) {
            const int k0 = kt * 64;
#pragma unroll
            for (int i = 0; i < 4; ++i)
                load_lds16(A + (size_t)(i * 32 + srow) * D_IN + k0 + scol, Alds + i * 2048 + wave * 512);
#pragma unroll
            for (int jj = 0; jj < 8; ++jj)
                load_lds16(B + (size_t)(jj * 32 + srow) * D_IN + k0 + scol, Blds + jj * 2048 + wave * 512);
            __syncthreads();
#pragma unroll
            for (int kc = 0; kc < 2; ++kc) {
                const int pc = ((kc * 4 + quad) ^ (lr & 7)) * 8;   // swizzled physical chunk
                bf16x8 af[4], bfv[8];
#pragma unroll
                for (int i = 0; i < 4; ++i)
                    af[i] = *(const bf16x8*)(Alds + (w_m + i * 16 + lr) * 64 + pc);
#pragma unroll
                for (int j = 0; j < 8; ++j)
                    bfv[j] = *(const bf16x8*)(Blds + (w_n + j * 16 + lr) * 64 + pc);
#pragma unroll
                for (int i = 0; i < 4; ++i)
#pragma unroll
                    for (int j = 0; j < 8; ++j)
                        acc[i][j] = __builtin_amdgcn_mfma_f32_16x16x32_bf16(af[i], bfv[j], acc[i][j], 0, 0, 0);
            }
            __syncthreads();
        }
    }

    // epilogue: relu(C + b1)*w2, reduce over this tile's n, accumulate to logits
    float b1v[8], w2v[8];
#pragma unroll
    for (int j = 0; j < 8; ++j) {
        int n = n0 + w_n + j * 16 + lr;              // C/D col = lane&15
        b1v[j] = b1[n];
        w2v[j] = w2[n];
    }
#pragma unroll
    for (int i = 0; i < 4; ++i) {
#pragma unroll
        for (int r = 0; r < 4; ++r) {
            float s = 0.f;
#pragma unroll
            for (int j = 0; j < 8; ++j) {
                float h = acc[i][j][r] + b1v[j];
                s += fmaxf(h, 0.f) * w2v[j];
            }
            s += __shfl_xor(s, 1, 64);
            s += __shfl_xor(s, 2, 64);
            s += __shfl_xor(s, 4, 64);
            s += __shfl_xor(s, 8, 64);
            if (lr == 0) {
                int m = m0 + w_m + i * 16 + quad * 4 + r;   // C/D row = quad*4 + reg
                atomicAdd(&out[(m & (BATCH - 1)) * T_STEPS + (m >> 2)], s);  // -> [b][t]
            }
        }
    }
}

// ------------- finish: soft output (blocks 0..63) + serial LIF scan (block 64) -------------
__global__ void __launch_bounds__(256)
finish(const float* __restrict__ logits,
       const float* __restrict__ bb2p, const float* __restrict__ br2p,
       float* __restrict__ out)
{
    if (blockIdx.x < 64) {
        int i = blockIdx.x * 256 + threadIdx.x;
        out[i] = logits[i] + bb2p[0];                // soft = boundary logits [b][t] + bb2
        return;
    }
    int b = threadIdx.x;
    if (b >= BATCH) return;
    const float bb2 = bb2p[0];
    const float br2 = br2p[0];
    const float* xb = logits + b * T_STEPS;          // boundary logits, [b][t]
    const float* xr = logits + M_ROWS + b * T_STEPS; // reset logits
    float* hb = out + M_ROWS + b * T_STEPS;
    float v = 0.f;
    for (int t0 = 0; t0 < T_STEPS; t0 += 4) {
        float4 xv = *(const float4*)(xb + t0);
        float4 rv = *(const float4*)(xr + t0);
#pragma unroll
        for (int u = 0; u < 4; ++u) {
            float x  = (u == 0 ? xv.x : u == 1 ? xv.y : u == 2 ? xv.z : xv.w) + bb2;
            float rl = (u == 0 ? rv.x : u == 1 ? rv.y : u == 2 ? rv.z : rv.w) + br2;
            v = v + (x - v) * 0.5f;                  // v += (x - v)/TAU, TAU=2 (exact)
            bool spike = (v >= 1.0f);                // heaviside(v - V_TH)
            hb[t0 + u] = spike ? 1.0f : 0.0f;
            v = (spike || (rl > 0.f)) ? 0.f : v;     // hard reset on spike or forced mask
        }
    }
}

extern "C" void kernel_launch(void* const* d_in, const int* in_sizes, int n_in,
                              void* d_out, int out_size, void* d_ws, size_t ws_size,
                              hipStream_t stream) {
    // dict order (confirmed): hidden, Wb1, bb1, Wb2, bb2, Wr1, br1, Wr2, br2
    const float* hidden = (const float*)d_in[0];   // [T,B,D] f32
    const float* Wb1    = (const float*)d_in[1];   // [D,H]
    const float* bb1    = (const float*)d_in[2];   // [H]
    const float* Wb2    = (const float*)d_in[3];   // [H,1]
    const float* bb2    = (const float*)d_in[4];   // [1]
    const float* Wr1    = (const float*)d_in[5];
    const float* br1    = (const float*)d_in[6];
    const float* Wr2    = (const float*)d_in[7];
    const float* br2    = (const float*)d_in[8];
    float* out = (float*)d_out;                    // f32: [soft B*T][hard B*T]

    // ws layout (96.13 MB): Xhi 32MB | Xlo 32MB | WThi 16MB | WTlo 16MB | logits 128KB
    unsigned short* Xhi  = (unsigned short*)d_ws;
    unsigned short* Xlo  = Xhi  + (size_t)M_ROWS * D_IN;
    unsigned short* WThi = Xlo  + (size_t)M_ROWS * D_IN;
    unsigned short* WTlo = WThi + (size_t)2 * H_DIM * D_IN;
    float* logits = (float*)(WTlo + (size_t)2 * H_DIM * D_IN);

    prep<<<dim3(18560), 256, 0, stream>>>(hidden, Wb1, Wr1, Xhi, Xlo, WThi, WTlo, logits);
    gemm_fused3<<<dim3(H_DIM / 256, M_ROWS / 128, 2), 256, 0, stream>>>(
        Xhi, Xlo, WThi, WTlo, bb1, br1, Wb2, Wr2, logits);
    finish<<<dim3(65), 256, 0, stream>>>(logits, bb2, br2, out);
}

// Round 12
// 970.535 us; speedup vs baseline: 2.0436x; 1.0171x over previous
//
#include <hip/hip_runtime.h>
#include <hip/hip_bf16.h>
#include <stdint.h>

// Problem constants: [T,B,D]=[4096,4,1024], H=4096. f32 inputs, f32 outputs.
// Outputs: soft [B,T] f32 at out[0..16384), hard [B,T] f32 at out[16384..32768).
#define T_STEPS 4096
#define BATCH   4
#define D_IN    1024
#define H_DIM   4096
#define M_ROWS  (T_STEPS * BATCH)

typedef __attribute__((ext_vector_type(8))) short bf16x8;
typedef __attribute__((ext_vector_type(4))) float f32x4;

__device__ __forceinline__ float b2f(unsigned short u) {
    union { unsigned int i; float f; } x; x.i = ((unsigned int)u) << 16; return x.f;
}
__device__ __forceinline__ unsigned short f2bf_rne(float f) {
    union { float f; unsigned int u; } v; v.f = f;
    return (unsigned short)((v.u + 0x7FFFu + ((v.u >> 16) & 1u)) >> 16);
}

__device__ __forceinline__ void load_lds16(const unsigned short* g, unsigned short* l) {
    __builtin_amdgcn_global_load_lds(
        (const __attribute__((address_space(1))) void*)g,
        (__attribute__((address_space(3))) void*)l, 16, 0, 0);
}

// ---------------- prep: zero logits + split X + split/transpose W (one launch) ----------------
// blocks [0,16384): split_x | [16384,18432): split_w | [18432,18560): zero logits
__global__ void __launch_bounds__(256)
prep(const float* __restrict__ hidden,
     const float* __restrict__ Wb1, const float* __restrict__ Wr1,
     unsigned short* __restrict__ Xhi, unsigned short* __restrict__ Xlo,
     unsigned short* __restrict__ WThi, unsigned short* __restrict__ WTlo,
     float* __restrict__ logits)
{
    __shared__ float tile[64][65];
    const int bid = blockIdx.x;
    const int t = threadIdx.x;

    if (bid < 16384) {
        // split hidden f32 -> (hi, lo) bf16, same layout; 256 float4 per block
        int i = bid * 256 + t;
        float4 x = ((const float4*)hidden)[i];
        ushort4 h, l;
        h.x = f2bf_rne(x.x); l.x = f2bf_rne(x.x - b2f(h.x));
        h.y = f2bf_rne(x.y); l.y = f2bf_rne(x.y - b2f(h.y));
        h.z = f2bf_rne(x.z); l.z = f2bf_rne(x.z - b2f(h.z));
        h.w = f2bf_rne(x.w); l.w = f2bf_rne(x.w - b2f(h.w));
        ((ushort4*)Xhi)[i] = h;
        ((ushort4*)Xlo)[i] = l;
    } else if (bid < 18432) {
        // transpose+split W [D][H] -> WT [H][D] for both matrices
        int wb  = bid - 16384;
        int z   = wb >> 10;                   // 0=boundary, 1=reset
        int rem = wb & 1023;
        int bx  = (rem & 63) * 64;            // H direction
        int by  = (rem >> 6) * 64;            // D direction
        const float* src = z ? Wr1 : Wb1;
        const size_t moff = (size_t)z * H_DIM * D_IN;
        const int c4 = (t & 15) * 4;
        const int r0 = (t >> 4) * 4;
#pragma unroll
        for (int rr = 0; rr < 4; ++rr) {
            int r = r0 + rr;
            float4 v = *(const float4*)(src + (size_t)(by + r) * H_DIM + bx + c4);
            tile[r][c4 + 0] = v.x; tile[r][c4 + 1] = v.y;
            tile[r][c4 + 2] = v.z; tile[r][c4 + 3] = v.w;
        }
        __syncthreads();
#pragma unroll
        for (int rr = 0; rr < 4; ++rr) {
            int c = r0 + rr;
            ushort4 h, l;
            float f0 = tile[c4 + 0][c], f1 = tile[c4 + 1][c];
            float f2 = tile[c4 + 2][c], f3 = tile[c4 + 3][c];
            h.x = f2bf_rne(f0); l.x = f2bf_rne(f0 - b2f(h.x));
            h.y = f2bf_rne(f1); l.y = f2bf_rne(f1 - b2f(h.y));
            h.z = f2bf_rne(f2); l.z = f2bf_rne(f2 - b2f(h.z));
            h.w = f2bf_rne(f3); l.w = f2bf_rne(f3 - b2f(h.w));
            size_t o = moff + (size_t)(bx + c) * D_IN + by + c4;
            *(ushort4*)(WThi + o) = h;
            *(ushort4*)(WTlo + o) = l;
        }
    } else {
        int i = (bid - 18432) * 256 + t;      // 128 blocks x 256 = 32768 = 2*M_ROWS
        logits[i] = 0.f;
    }
}

// ------------- fused split-f32 GEMM + relu + (.)@W2 reduction -------------
// SINGLE K-loop computing all 3 split products per K-chunk:
//   acc += Xhi.Bhi + Xlo.Bhi + Xhi.Blo   (B_hi frags read once, feed 2 MFMA sets)
// Block tile 128m x 256n, BK=32, 4 waves, wave tile 64m x 128n (4x8 frags, 16x16x32 bf16).
// LDS 48 KB: Ahi/Alo 128x32, Bhi/Blo 256x32. XOR swizzle (4 chunks/row): global chunk c
// of row r at phys slot c^(r&3) -> balanced 8 lanes per 4-bank group, 0 conflicts.
// __launch_bounds__(256,2): acc=128 AGPR; VGPR capped so unified <=256 -> 2 waves/SIMD (r11 lesson).
__global__ void __launch_bounds__(256, 2)
gemm_fused3(const unsigned short* __restrict__ Xhi, const unsigned short* __restrict__ Xlo,
            const unsigned short* __restrict__ WThi, const unsigned short* __restrict__ WTlo,
            const float* __restrict__ b1b, const float* __restrict__ b1r,
            const float* __restrict__ w2b, const float* __restrict__ w2r,
            float* __restrict__ logits)              // [2][B][T] f32, atomically accumulated
{
    __shared__ __align__(16) unsigned short Ahi_s[128 * 32];   // 8 KB
    __shared__ __align__(16) unsigned short Alo_s[128 * 32];   // 8 KB
    __shared__ __align__(16) unsigned short Bhi_s[256 * 32];   // 16 KB
    __shared__ __align__(16) unsigned short Blo_s[256 * 32];   // 16 KB

    const int t    = threadIdx.x;
    const int wave = t >> 6;
    const int lane = t & 63;
    const int quad = lane >> 4;
    const int lr   = lane & 15;
    const int w_m  = (wave & 1) * 64;
    const int w_n  = (wave >> 1) * 128;

    const int mat = blockIdx.z;
    const int n0  = blockIdx.x * 256;
    const int m0  = blockIdx.y * 128;

    const size_t aoff = (size_t)m0 * D_IN;
    const size_t boff = (size_t)mat * H_DIM * D_IN + (size_t)n0 * D_IN;
    const unsigned short* Ah = Xhi + aoff;
    const unsigned short* Al = Xlo + aoff;
    const unsigned short* Bh = WThi + boff;
    const unsigned short* Bl = WTlo + boff;
    const float* b1 = mat ? b1r : b1b;
    const float* w2 = mat ? w2r : w2b;
    float* out = logits + mat * M_ROWS;

    // staging (BK=32, rows of 4x16B chunks): instr i covers tile rows i*64 + (t>>2),
    // phys chunk t&3; XOR-swizzled source chunk (t&3)^((t>>2)&3).
    // LDS dest (wave-uniform + lane*16B) = i*2048 + wave*512 elems; phys offset == t*8 elems.
    const int srow = t >> 2;
    const int scol = (((t & 3) ^ (srow & 3)) * 8);

    f32x4 acc[4][8] = {};

#pragma unroll 1
    for (int kt = 0; kt < D_IN / 32; ++kt) {
        const int k0 = kt * 32;
#pragma unroll
        for (int i = 0; i < 2; ++i)
            load_lds16(Ah + (size_t)(i * 64 + srow) * D_IN + k0 + scol, Ahi_s + i * 2048 + wave * 512);
#pragma unroll
        for (int i = 0; i < 2; ++i)
            load_lds16(Al + (size_t)(i * 64 + srow) * D_IN + k0 + scol, Alo_s + i * 2048 + wave * 512);
#pragma unroll
        for (int i = 0; i < 4; ++i)
            load_lds16(Bh + (size_t)(i * 64 + srow) * D_IN + k0 + scol, Bhi_s + i * 2048 + wave * 512);
#pragma unroll
        for (int i = 0; i < 4; ++i)
            load_lds16(Bl + (size_t)(i * 64 + srow) * D_IN + k0 + scol, Blo_s + i * 2048 + wave * 512);
        __syncthreads();

        bf16x8 afh[4], afl[4], bfv[8];
#pragma unroll
        for (int i = 0; i < 4; ++i) {
            int row = w_m + i * 16 + lr;
            int off = row * 32 + ((quad ^ (row & 3)) * 8);
            afh[i] = *(const bf16x8*)(Ahi_s + off);
            afl[i] = *(const bf16x8*)(Alo_s + off);
        }
#pragma unroll
        for (int j = 0; j < 8; ++j) {
            int row = w_n + j * 16 + lr;
            bfv[j] = *(const bf16x8*)(Bhi_s + row * 32 + ((quad ^ (row & 3)) * 8));
        }
#pragma unroll
        for (int i = 0; i < 4; ++i)
#pragma unroll
            for (int j = 0; j < 8; ++j)
                acc[i][j] = __builtin_amdgcn_mfma_f32_16x16x32_bf16(afh[i], bfv[j], acc[i][j], 0, 0, 0);
#pragma unroll
        for (int i = 0; i < 4; ++i)
#pragma unroll
            for (int j = 0; j < 8; ++j)
                acc[i][j] = __builtin_amdgcn_mfma_f32_16x16x32_bf16(afl[i], bfv[j], acc[i][j], 0, 0, 0);
#pragma unroll
        for (int j = 0; j < 8; ++j) {
            int row = w_n + j * 16 + lr;
            bfv[j] = *(const bf16x8*)(Blo_s + row * 32 + ((quad ^ (row & 3)) * 8));
        }
#pragma unroll
        for (int i = 0; i < 4; ++i)
#pragma unroll
            for (int j = 0; j < 8; ++j)
                acc[i][j] = __builtin_amdgcn_mfma_f32_16x16x32_bf16(afh[i], bfv[j], acc[i][j], 0, 0, 0);
        __syncthreads();
    }

    // epilogue: relu(C + b1)*w2, reduce over this tile's n, accumulate to logits
    float b1v[8], w2v[8];
#pragma unroll
    for (int j = 0; j < 8; ++j) {
        int n = n0 + w_n + j * 16 + lr;              // C/D col = lane&15
        b1v[j] = b1[n];
        w2v[j] = w2[n];
    }
#pragma unroll
    for (int i = 0; i < 4; ++i) {
#pragma unroll
        for (int r = 0; r < 4; ++r) {
            float s = 0.f;
#pragma unroll
            for (int j = 0; j < 8; ++j) {
                float h = acc[i][j][r] + b1v[j];
                s += fmaxf(h, 0.f) * w2v[j];
            }
            s += __shfl_xor(s, 1, 64);
            s += __shfl_xor(s, 2, 64);
            s += __shfl_xor(s, 4, 64);
            s += __shfl_xor(s, 8, 64);
            if (lr == 0) {
                int m = m0 + w_m + i * 16 + quad * 4 + r;   // C/D row = quad*4 + reg
                atomicAdd(&out[(m & (BATCH - 1)) * T_STEPS + (m >> 2)], s);  // -> [b][t]
            }
        }
    }
}

// ------------- finish: soft output (blocks 0..63) + serial LIF scan (block 64) -------------
__global__ void __launch_bounds__(256)
finish(const float* __restrict__ logits,
       const float* __restrict__ bb2p, const float* __restrict__ br2p,
       float* __restrict__ out)
{
    if (blockIdx.x < 64) {
        int i = blockIdx.x * 256 + threadIdx.x;
        out[i] = logits[i] + bb2p[0];                // soft = boundary logits [b][t] + bb2
        return;
    }
    int b = threadIdx.x;
    if (b >= BATCH) return;
    const float bb2 = bb2p[0];
    const float br2 = br2p[0];
    const float* xb = logits + b * T_STEPS;          // boundary logits, [b][t]
    const float* xr = logits + M_ROWS + b * T_STEPS; // reset logits
    float* hb = out + M_ROWS + b * T_STEPS;
    float v = 0.f;
    for (int t0 = 0; t0 < T_STEPS; t0 += 4) {
        float4 xv = *(const float4*)(xb + t0);
        float4 rv = *(const float4*)(xr + t0);
#pragma unroll
        for (int u = 0; u < 4; ++u) {
            float x  = (u == 0 ? xv.x : u == 1 ? xv.y : u == 2 ? xv.z : xv.w) + bb2;
            float rl = (u == 0 ? rv.x : u == 1 ? rv.y : u == 2 ? rv.z : rv.w) + br2;
            v = v + (x - v) * 0.5f;                  // v += (x - v)/TAU, TAU=2 (exact)
            bool spike = (v >= 1.0f);                // heaviside(v - V_TH)
            hb[t0 + u] = spike ? 1.0f : 0.0f;
            v = (spike || (rl > 0.f)) ? 0.f : v;     // hard reset on spike or forced mask
        }
    }
}

extern "C" void kernel_launch(void* const* d_in, const int* in_sizes, int n_in,
                              void* d_out, int out_size, void* d_ws, size_t ws_size,
                              hipStream_t stream) {
    // dict order (confirmed): hidden, Wb1, bb1, Wb2, bb2, Wr1, br1, Wr2, br2
    const float* hidden = (const float*)d_in[0];   // [T,B,D] f32
    const float* Wb1    = (const float*)d_in[1];   // [D,H]
    const float* bb1    = (const float*)d_in[2];   // [H]
    const float* Wb2    = (const float*)d_in[3];   // [H,1]
    const float* bb2    = (const float*)d_in[4];   // [1]
    const float* Wr1    = (const float*)d_in[5];
    const float* br1    = (const float*)d_in[6];
    const float* Wr2    = (const float*)d_in[7];
    const float* br2    = (const float*)d_in[8];
    float* out = (float*)d_out;                    // f32: [soft B*T][hard B*T]

    // ws layout (96.13 MB): Xhi 32MB | Xlo 32MB | WThi 16MB | WTlo 16MB | logits 128KB
    unsigned short* Xhi  = (unsigned short*)d_ws;
    unsigned short* Xlo  = Xhi  + (size_t)M_ROWS * D_IN;
    unsigned short* WThi = Xlo  + (size_t)M_ROWS * D_IN;
    unsigned short* WTlo = WThi + (size_t)2 * H_DIM * D_IN;
    float* logits = (float*)(WTlo + (size_t)2 * H_DIM * D_IN);

    prep<<<dim3(18560), 256, 0, stream>>>(hidden, Wb1, Wr1, Xhi, Xlo, WThi, WTlo, logits);
    gemm_fused3<<<dim3(H_DIM / 256, M_ROWS / 128, 2), 256, 0, stream>>>(
        Xhi, Xlo, WThi, WTlo, bb1, br1, Wb2, Wr2, logits);
    finish<<<dim3(65), 256, 0, stream>>>(logits, bb2, br2, out);
}

// Round 13
// 957.026 us; speedup vs baseline: 2.0725x; 1.0141x over previous
//
#include <hip/hip_runtime.h>
#include <hip/hip_bf16.h>
#include <stdint.h>

// Problem constants: [T,B,D]=[4096,4,1024], H=4096. f32 inputs, f32 outputs.
// Outputs: soft [B,T] f32 at out[0..16384), hard [B,T] f32 at out[16384..32768).
#define T_STEPS 4096
#define BATCH   4
#define D_IN    1024
#define H_DIM   4096
#define M_ROWS  (T_STEPS * BATCH)

typedef __attribute__((ext_vector_type(8))) short bf16x8;
typedef __attribute__((ext_vector_type(4))) float f32x4;

__device__ __forceinline__ float b2f(unsigned short u) {
    union { unsigned int i; float f; } x; x.i = ((unsigned int)u) << 16; return x.f;
}
__device__ __forceinline__ unsigned short f2bf_rne(float f) {
    union { float f; unsigned int u; } v; v.f = f;
    return (unsigned short)((v.u + 0x7FFFu + ((v.u >> 16) & 1u)) >> 16);
}

__device__ __forceinline__ void load_lds16(const unsigned short* g, unsigned short* l) {
    __builtin_amdgcn_global_load_lds(
        (const __attribute__((address_space(1))) void*)g,
        (__attribute__((address_space(3))) void*)l, 16, 0, 0);
}

// ---------------- prep: zero logits + split X + split/transpose W (one launch) ----------------
// blocks [0,16384): split_x | [16384,18432): split_w | [18432,18560): zero logits
__global__ void __launch_bounds__(256)
prep(const float* __restrict__ hidden,
     const float* __restrict__ Wb1, const float* __restrict__ Wr1,
     unsigned short* __restrict__ Xhi, unsigned short* __restrict__ Xlo,
     unsigned short* __restrict__ WThi, unsigned short* __restrict__ WTlo,
     float* __restrict__ logits)
{
    __shared__ float tile[64][65];
    const int bid = blockIdx.x;
    const int t = threadIdx.x;

    if (bid < 16384) {
        // split hidden f32 -> (hi, lo) bf16, same layout; 256 float4 per block
        int i = bid * 256 + t;
        float4 x = ((const float4*)hidden)[i];
        ushort4 h, l;
        h.x = f2bf_rne(x.x); l.x = f2bf_rne(x.x - b2f(h.x));
        h.y = f2bf_rne(x.y); l.y = f2bf_rne(x.y - b2f(h.y));
        h.z = f2bf_rne(x.z); l.z = f2bf_rne(x.z - b2f(h.z));
        h.w = f2bf_rne(x.w); l.w = f2bf_rne(x.w - b2f(h.w));
        ((ushort4*)Xhi)[i] = h;
        ((ushort4*)Xlo)[i] = l;
    } else if (bid < 18432) {
        // transpose+split W [D][H] -> WT [H][D] for both matrices
        int wb  = bid - 16384;
        int z   = wb >> 10;                   // 0=boundary, 1=reset
        int rem = wb & 1023;
        int bx  = (rem & 63) * 64;            // H direction
        int by  = (rem >> 6) * 64;            // D direction
        const float* src = z ? Wr1 : Wb1;
        const size_t moff = (size_t)z * H_DIM * D_IN;
        const int c4 = (t & 15) * 4;
        const int r0 = (t >> 4) * 4;
#pragma unroll
        for (int rr = 0; rr < 4; ++rr) {
            int r = r0 + rr;
            float4 v = *(const float4*)(src + (size_t)(by + r) * H_DIM + bx + c4);
            tile[r][c4 + 0] = v.x; tile[r][c4 + 1] = v.y;
            tile[r][c4 + 2] = v.z; tile[r][c4 + 3] = v.w;
        }
        __syncthreads();
#pragma unroll
        for (int rr = 0; rr < 4; ++rr) {
            int c = r0 + rr;
            ushort4 h, l;
            float f0 = tile[c4 + 0][c], f1 = tile[c4 + 1][c];
            float f2 = tile[c4 + 2][c], f3 = tile[c4 + 3][c];
            h.x = f2bf_rne(f0); l.x = f2bf_rne(f0 - b2f(h.x));
            h.y = f2bf_rne(f1); l.y = f2bf_rne(f1 - b2f(h.y));
            h.z = f2bf_rne(f2); l.z = f2bf_rne(f2 - b2f(h.z));
            h.w = f2bf_rne(f3); l.w = f2bf_rne(f3 - b2f(h.w));
            size_t o = moff + (size_t)(bx + c) * D_IN + by + c4;
            *(ushort4*)(WThi + o) = h;
            *(ushort4*)(WTlo + o) = l;
        }
    } else {
        int i = (bid - 18432) * 256 + t;      // 128 blocks x 256 = 32768 = 2*M_ROWS
        logits[i] = 0.f;
    }
}

// ------------- fused split-f32 GEMM + relu + (.)@W2 reduction -------------
// SINGLE K-loop computing all 3 split products per K-chunk:
//   acc += Xhi.Bhi + Xlo.Bhi + Xhi.Blo   (B_hi frags read once, feed 2 MFMA sets)
// Block tile 128m x 256n, BK=32, 4 waves, wave tile 64m x 128n (4x8 frags, 16x16x32 bf16).
// LDS 48 KB: Ahi/Alo 128x32, Bhi/Blo 256x32.
// XOR swizzle (r12 POST-MORTEM FIX): 32-elem rows stride 64 B = HALF the bank span, so
// bank-group = (row&1)*16 + chunk*4. Swizzle must draw on (row>>1)&3 (not row&3):
//   phys chunk p = c ^ ((row>>1)&3)  ->  over 16 consecutive rows, (row&1,(row>>1)&3)
//   covers all 8 bank-groups exactly twice -> 2 lanes/group = conflict-free (m136).
// __launch_bounds__(256,2): acc=128 AGPR; VGPR capped so unified <=256 -> 2 waves/SIMD (r11 lesson).
__global__ void __launch_bounds__(256, 2)
gemm_fused3(const unsigned short* __restrict__ Xhi, const unsigned short* __restrict__ Xlo,
            const unsigned short* __restrict__ WThi, const unsigned short* __restrict__ WTlo,
            const float* __restrict__ b1b, const float* __restrict__ b1r,
            const float* __restrict__ w2b, const float* __restrict__ w2r,
            float* __restrict__ logits)              // [2][B][T] f32, atomically accumulated
{
    __shared__ __align__(16) unsigned short Ahi_s[128 * 32];   // 8 KB
    __shared__ __align__(16) unsigned short Alo_s[128 * 32];   // 8 KB
    __shared__ __align__(16) unsigned short Bhi_s[256 * 32];   // 16 KB
    __shared__ __align__(16) unsigned short Blo_s[256 * 32];   // 16 KB

    const int t    = threadIdx.x;
    const int wave = t >> 6;
    const int lane = t & 63;
    const int quad = lane >> 4;
    const int lr   = lane & 15;
    const int w_m  = (wave & 1) * 64;
    const int w_n  = (wave >> 1) * 128;

    const int mat = blockIdx.z;
    const int n0  = blockIdx.x * 256;
    const int m0  = blockIdx.y * 128;

    const size_t aoff = (size_t)m0 * D_IN;
    const size_t boff = (size_t)mat * H_DIM * D_IN + (size_t)n0 * D_IN;
    const unsigned short* Ah = Xhi + aoff;
    const unsigned short* Al = Xlo + aoff;
    const unsigned short* Bh = WThi + boff;
    const unsigned short* Bl = WTlo + boff;
    const float* b1 = mat ? b1r : b1b;
    const float* w2 = mat ? w2r : w2b;
    float* out = logits + mat * M_ROWS;

    // staging (BK=32): thread t fills phys chunk (t&3) of row (t>>2)+i*64.
    // Source global chunk = (t&3) ^ ((row>>1)&3) = (t&3) ^ ((t>>3)&3)  (i*64 is 0 mod 4 after >>1).
    const int srow = t >> 2;
    const int scol = (((t & 3) ^ ((t >> 3) & 3)) * 8);

    f32x4 acc[4][8] = {};

#pragma unroll 1
    for (int kt = 0; kt < D_IN / 32; ++kt) {
        const int k0 = kt * 32;
#pragma unroll
        for (int i = 0; i < 2; ++i)
            load_lds16(Ah + (size_t)(i * 64 + srow) * D_IN + k0 + scol, Ahi_s + i * 2048 + wave * 512);
#pragma unroll
        for (int i = 0; i < 2; ++i)
            load_lds16(Al + (size_t)(i * 64 + srow) * D_IN + k0 + scol, Alo_s + i * 2048 + wave * 512);
#pragma unroll
        for (int i = 0; i < 4; ++i)
            load_lds16(Bh + (size_t)(i * 64 + srow) * D_IN + k0 + scol, Bhi_s + i * 2048 + wave * 512);
#pragma unroll
        for (int i = 0; i < 4; ++i)
            load_lds16(Bl + (size_t)(i * 64 + srow) * D_IN + k0 + scol, Blo_s + i * 2048 + wave * 512);
        __syncthreads();

        bf16x8 afh[4], afl[4], bfv[8];
#pragma unroll
        for (int i = 0; i < 4; ++i) {
            int row = w_m + i * 16 + lr;
            int off = row * 32 + ((quad ^ ((row >> 1) & 3)) * 8);
            afh[i] = *(const bf16x8*)(Ahi_s + off);
            afl[i] = *(const bf16x8*)(Alo_s + off);
        }
#pragma unroll
        for (int j = 0; j < 8; ++j) {
            int row = w_n + j * 16 + lr;
            bfv[j] = *(const bf16x8*)(Bhi_s + row * 32 + ((quad ^ ((row >> 1) & 3)) * 8));
        }
#pragma unroll
        for (int i = 0; i < 4; ++i)
#pragma unroll
            for (int j = 0; j < 8; ++j)
                acc[i][j] = __builtin_amdgcn_mfma_f32_16x16x32_bf16(afh[i], bfv[j], acc[i][j], 0, 0, 0);
#pragma unroll
        for (int i = 0; i < 4; ++i)
#pragma unroll
            for (int j = 0; j < 8; ++j)
                acc[i][j] = __builtin_amdgcn_mfma_f32_16x16x32_bf16(afl[i], bfv[j], acc[i][j], 0, 0, 0);
#pragma unroll
        for (int j = 0; j < 8; ++j) {
            int row = w_n + j * 16 + lr;
            bfv[j] = *(const bf16x8*)(Blo_s + row * 32 + ((quad ^ ((row >> 1) & 3)) * 8));
        }
#pragma unroll
        for (int i = 0; i < 4; ++i)
#pragma unroll
            for (int j = 0; j < 8; ++j)
                acc[i][j] = __builtin_amdgcn_mfma_f32_16x16x32_bf16(afh[i], bfv[j], acc[i][j], 0, 0, 0);
        __syncthreads();
    }

    // epilogue: relu(C + b1)*w2, reduce over this tile's n, accumulate to logits
    float b1v[8], w2v[8];
#pragma unroll
    for (int j = 0; j < 8; ++j) {
        int n = n0 + w_n + j * 16 + lr;              // C/D col = lane&15
        b1v[j] = b1[n];
        w2v[j] = w2[n];
    }
#pragma unroll
    for (int i = 0; i < 4; ++i) {
#pragma unroll
        for (int r = 0; r < 4; ++r) {
            float s = 0.f;
#pragma unroll
            for (int j = 0; j < 8; ++j) {
                float h = acc[i][j][r] + b1v[j];
                s += fmaxf(h, 0.f) * w2v[j];
            }
            s += __shfl_xor(s, 1, 64);
            s += __shfl_xor(s, 2, 64);
            s += __shfl_xor(s, 4, 64);
            s += __shfl_xor(s, 8, 64);
            if (lr == 0) {
                int m = m0 + w_m + i * 16 + quad * 4 + r;   // C/D row = quad*4 + reg
                atomicAdd(&out[(m & (BATCH - 1)) * T_STEPS + (m >> 2)], s);  // -> [b][t]
            }
        }
    }
}

// ------------- finish: soft output (blocks 0..63) + serial LIF scan (block 64) -------------
__global__ void __launch_bounds__(256)
finish(const float* __restrict__ logits,
       const float* __restrict__ bb2p, const float* __restrict__ br2p,
       float* __restrict__ out)
{
    if (blockIdx.x < 64) {
        int i = blockIdx.x * 256 + threadIdx.x;
        out[i] = logits[i] + bb2p[0];                // soft = boundary logits [b][t] + bb2
        return;
    }
    int b = threadIdx.x;
    if (b >= BATCH) return;
    const float bb2 = bb2p[0];
    const float br2 = br2p[0];
    const float* xb = logits + b * T_STEPS;          // boundary logits, [b][t]
    const float* xr = logits + M_ROWS + b * T_STEPS; // reset logits
    float* hb = out + M_ROWS + b * T_STEPS;
    float v = 0.f;
    for (int t0 = 0; t0 < T_STEPS; t0 += 4) {
        float4 xv = *(const float4*)(xb + t0);
        float4 rv = *(const float4*)(xr + t0);
#pragma unroll
        for (int u = 0; u < 4; ++u) {
            float x  = (u == 0 ? xv.x : u == 1 ? xv.y : u == 2 ? xv.z : xv.w) + bb2;
            float rl = (u == 0 ? rv.x : u == 1 ? rv.y : u == 2 ? rv.z : rv.w) + br2;
            v = v + (x - v) * 0.5f;                  // v += (x - v)/TAU, TAU=2 (exact)
            bool spike = (v >= 1.0f);                // heaviside(v - V_TH)
            hb[t0 + u] = spike ? 1.0f : 0.0f;
            v = (spike || (rl > 0.f)) ? 0.f : v;     // hard reset on spike or forced mask
        }
    }
}

extern "C" void kernel_launch(void* const* d_in, const int* in_sizes, int n_in,
                              void* d_out, int out_size, void* d_ws, size_t ws_size,
                              hipStream_t stream) {
    // dict order (confirmed): hidden, Wb1, bb1, Wb2, bb2, Wr1, br1, Wr2, br2
    const float* hidden = (const float*)d_in[0];   // [T,B,D] f32
    const float* Wb1    = (const float*)d_in[1];   // [D,H]
    const float* bb1    = (const float*)d_in[2];   // [H]
    const float* Wb2    = (const float*)d_in[3];   // [H,1]
    const float* bb2    = (const float*)d_in[4];   // [1]
    const float* Wr1    = (const float*)d_in[5];
    const float* br1    = (const float*)d_in[6];
    const float* Wr2    = (const float*)d_in[7];
    const float* br2    = (const float*)d_in[8];
    float* out = (float*)d_out;                    // f32: [soft B*T][hard B*T]

    // ws layout (96.13 MB): Xhi 32MB | Xlo 32MB | WThi 16MB | WTlo 16MB | logits 128KB
    unsigned short* Xhi  = (unsigned short*)d_ws;
    unsigned short* Xlo  = Xhi  + (size_t)M_ROWS * D_IN;
    unsigned short* WThi = Xlo  + (size_t)M_ROWS * D_IN;
    unsigned short* WTlo = WThi + (size_t)2 * H_DIM * D_IN;
    float* logits = (float*)(WTlo + (size_t)2 * H_DIM * D_IN);

    prep<<<dim3(18560), 256, 0, stream>>>(hidden, Wb1, Wr1, Xhi, Xlo, WThi, WTlo, logits);
    gemm_fused3<<<dim3(H_DIM / 256, M_ROWS / 128, 2), 256, 0, stream>>>(
        Xhi, Xlo, WThi, WTlo, bb1, br1, Wb2, Wr2, logits);
    finish<<<dim3(65), 256, 0, stream>>>(logits, bb2, br2, out);
}

// Round 14
// 922.116 us; speedup vs baseline: 2.1510x; 1.0379x over previous
//
#include <hip/hip_runtime.h>
#include <hip/hip_bf16.h>
#include <stdint.h>

// Problem constants: [T,B,D]=[4096,4,1024], H=4096. f32 inputs, f32 outputs.
// Outputs: soft [B,T] f32 at out[0..16384), hard [B,T] f32 at out[16384..32768).
#define T_STEPS 4096
#define BATCH   4
#define D_IN    1024
#define H_DIM   4096
#define M_ROWS  (T_STEPS * BATCH)

typedef __attribute__((ext_vector_type(8))) short bf16x8;
typedef __attribute__((ext_vector_type(4))) float f32x4;

__device__ __forceinline__ float b2f(unsigned short u) {
    union { unsigned int i; float f; } x; x.i = ((unsigned int)u) << 16; return x.f;
}
__device__ __forceinline__ unsigned short f2bf_rne(float f) {
    union { float f; unsigned int u; } v; v.f = f;
    return (unsigned short)((v.u + 0x7FFFu + ((v.u >> 16) & 1u)) >> 16);
}

__device__ __forceinline__ void load_lds16(const unsigned short* g, unsigned short* l) {
    __builtin_amdgcn_global_load_lds(
        (const __attribute__((address_space(1))) void*)g,
        (__attribute__((address_space(3))) void*)l, 16, 0, 0);
}

// ---------------- prep: split X (fat blocks) + split/transpose W + zero logits ----------------
// blocks [0,4096): split_x (4 float4/thread) | [4096,6144): split_w | [6144,6176): zero logits
__global__ void __launch_bounds__(256)
prep(const float* __restrict__ hidden,
     const float* __restrict__ Wb1, const float* __restrict__ Wr1,
     unsigned short* __restrict__ Xhi, unsigned short* __restrict__ Xlo,
     unsigned short* __restrict__ WThi, unsigned short* __restrict__ WTlo,
     float* __restrict__ logits)
{
    __shared__ float tile[64][65];
    const int bid = blockIdx.x;
    const int t = threadIdx.x;

    if (bid < 4096) {
        // split hidden f32 -> (hi, lo) bf16, same layout; 4 coalesced float4 per thread
#pragma unroll
        for (int j = 0; j < 4; ++j) {
            int i = bid * 1024 + j * 256 + t;
            float4 x = ((const float4*)hidden)[i];
            ushort4 h, l;
            h.x = f2bf_rne(x.x); l.x = f2bf_rne(x.x - b2f(h.x));
            h.y = f2bf_rne(x.y); l.y = f2bf_rne(x.y - b2f(h.y));
            h.z = f2bf_rne(x.z); l.z = f2bf_rne(x.z - b2f(h.z));
            h.w = f2bf_rne(x.w); l.w = f2bf_rne(x.w - b2f(h.w));
            ((ushort4*)Xhi)[i] = h;
            ((ushort4*)Xlo)[i] = l;
        }
    } else if (bid < 6144) {
        // transpose+split W [D][H] -> WT [H][D] for both matrices
        int wb  = bid - 4096;
        int z   = wb >> 10;                   // 0=boundary, 1=reset
        int rem = wb & 1023;
        int bx  = (rem & 63) * 64;            // H direction
        int by  = (rem >> 6) * 64;            // D direction
        const float* src = z ? Wr1 : Wb1;
        const size_t moff = (size_t)z * H_DIM * D_IN;
        const int c4 = (t & 15) * 4;
        const int r0 = (t >> 4) * 4;
#pragma unroll
        for (int rr = 0; rr < 4; ++rr) {
            int r = r0 + rr;
            float4 v = *(const float4*)(src + (size_t)(by + r) * H_DIM + bx + c4);
            tile[r][c4 + 0] = v.x; tile[r][c4 + 1] = v.y;
            tile[r][c4 + 2] = v.z; tile[r][c4 + 3] = v.w;
        }
        __syncthreads();
#pragma unroll
        for (int rr = 0; rr < 4; ++rr) {
            int c = r0 + rr;
            ushort4 h, l;
            float f0 = tile[c4 + 0][c], f1 = tile[c4 + 1][c];
            float f2 = tile[c4 + 2][c], f3 = tile[c4 + 3][c];
            h.x = f2bf_rne(f0); l.x = f2bf_rne(f0 - b2f(h.x));
            h.y = f2bf_rne(f1); l.y = f2bf_rne(f1 - b2f(h.y));
            h.z = f2bf_rne(f2); l.z = f2bf_rne(f2 - b2f(h.z));
            h.w = f2bf_rne(f3); l.w = f2bf_rne(f3 - b2f(h.w));
            size_t o = moff + (size_t)(bx + c) * D_IN + by + c4;
            *(ushort4*)(WThi + o) = h;
            *(ushort4*)(WTlo + o) = l;
        }
    } else {
#pragma unroll
        for (int j = 0; j < 4; ++j)
            logits[(bid - 6144) * 1024 + j * 256 + t] = 0.f;   // 32 blocks x 1024 = 32768
    }
}

// ------------- fused split-f32 GEMM + relu + (.)@W2 reduction -------------
// SINGLE K-loop, 3 split products per K-chunk: acc += Xhi.Bhi + Xlo.Bhi + Xhi.Blo
// Block tile 128m x 256n, BK=32, 4 waves, wave tile 64m x 128n (4x8 frags, 16x16x32 bf16).
// LDS 48 KB. XOR swizzle on (row>>1)&3 (r13-proven conflict-free for 64 B rows).
// All 24 fragment loads hoisted above the MFMA sets (lgkmcnt overlap across all 3 sets).
// __launch_bounds__(256,2): acc=128 AGPR; VGPR capped so unified <=256 -> 2 waves/SIMD.
__global__ void __launch_bounds__(256, 2)
gemm_fused3(const unsigned short* __restrict__ Xhi, const unsigned short* __restrict__ Xlo,
            const unsigned short* __restrict__ WThi, const unsigned short* __restrict__ WTlo,
            const float* __restrict__ b1b, const float* __restrict__ b1r,
            const float* __restrict__ w2b, const float* __restrict__ w2r,
            float* __restrict__ logits)              // [2][B][T] f32, atomically accumulated
{
    __shared__ __align__(16) unsigned short Ahi_s[128 * 32];   // 8 KB
    __shared__ __align__(16) unsigned short Alo_s[128 * 32];   // 8 KB
    __shared__ __align__(16) unsigned short Bhi_s[256 * 32];   // 16 KB
    __shared__ __align__(16) unsigned short Blo_s[256 * 32];   // 16 KB

    const int t    = threadIdx.x;
    const int wave = t >> 6;
    const int lane = t & 63;
    const int quad = lane >> 4;
    const int lr   = lane & 15;
    const int w_m  = (wave & 1) * 64;
    const int w_n  = (wave >> 1) * 128;

    const int mat = blockIdx.z;
    const int n0  = blockIdx.x * 256;
    const int m0  = blockIdx.y * 128;

    const size_t aoff = (size_t)m0 * D_IN;
    const size_t boff = (size_t)mat * H_DIM * D_IN + (size_t)n0 * D_IN;
    const unsigned short* Ah = Xhi + aoff;
    const unsigned short* Al = Xlo + aoff;
    const unsigned short* Bh = WThi + boff;
    const unsigned short* Bl = WTlo + boff;
    const float* b1 = mat ? b1r : b1b;
    const float* w2 = mat ? w2r : w2b;
    float* out = logits + mat * M_ROWS;

    // staging (BK=32): thread t fills phys chunk (t&3) of row (t>>2)+i*64.
    // Source global chunk = (t&3) ^ ((row>>1)&3) = (t&3) ^ ((t>>3)&3).
    const int srow = t >> 2;
    const int scol = (((t & 3) ^ ((t >> 3) & 3)) * 8);

    f32x4 acc[4][8] = {};

#pragma unroll 1
    for (int kt = 0; kt < D_IN / 32; ++kt) {
        const int k0 = kt * 32;
#pragma unroll
        for (int i = 0; i < 2; ++i)
            load_lds16(Ah + (size_t)(i * 64 + srow) * D_IN + k0 + scol, Ahi_s + i * 2048 + wave * 512);
#pragma unroll
        for (int i = 0; i < 2; ++i)
            load_lds16(Al + (size_t)(i * 64 + srow) * D_IN + k0 + scol, Alo_s + i * 2048 + wave * 512);
#pragma unroll
        for (int i = 0; i < 4; ++i)
            load_lds16(Bh + (size_t)(i * 64 + srow) * D_IN + k0 + scol, Bhi_s + i * 2048 + wave * 512);
#pragma unroll
        for (int i = 0; i < 4; ++i)
            load_lds16(Bl + (size_t)(i * 64 + srow) * D_IN + k0 + scol, Blo_s + i * 2048 + wave * 512);
        __syncthreads();

        // all fragment loads up front; compiler issues fine-grained lgkmcnt before each MFMA set
        bf16x8 afh[4], afl[4], bfh[8], bfl[8];
#pragma unroll
        for (int i = 0; i < 4; ++i) {
            int row = w_m + i * 16 + lr;
            int off = row * 32 + ((quad ^ ((row >> 1) & 3)) * 8);
            afh[i] = *(const bf16x8*)(Ahi_s + off);
            afl[i] = *(const bf16x8*)(Alo_s + off);
        }
#pragma unroll
        for (int j = 0; j < 8; ++j) {
            int row = w_n + j * 16 + lr;
            int off = row * 32 + ((quad ^ ((row >> 1) & 3)) * 8);
            bfh[j] = *(const bf16x8*)(Bhi_s + off);
            bfl[j] = *(const bf16x8*)(Blo_s + off);
        }
#pragma unroll
        for (int i = 0; i < 4; ++i)
#pragma unroll
            for (int j = 0; j < 8; ++j)
                acc[i][j] = __builtin_amdgcn_mfma_f32_16x16x32_bf16(afh[i], bfh[j], acc[i][j], 0, 0, 0);
#pragma unroll
        for (int i = 0; i < 4; ++i)
#pragma unroll
            for (int j = 0; j < 8; ++j)
                acc[i][j] = __builtin_amdgcn_mfma_f32_16x16x32_bf16(afl[i], bfh[j], acc[i][j], 0, 0, 0);
#pragma unroll
        for (int i = 0; i < 4; ++i)
#pragma unroll
            for (int j = 0; j < 8; ++j)
                acc[i][j] = __builtin_amdgcn_mfma_f32_16x16x32_bf16(afh[i], bfl[j], acc[i][j], 0, 0, 0);
        __syncthreads();
    }

    // epilogue: relu(C + b1)*w2, reduce over this tile's n, accumulate to logits
    float b1v[8], w2v[8];
#pragma unroll
    for (int j = 0; j < 8; ++j) {
        int n = n0 + w_n + j * 16 + lr;              // C/D col = lane&15
        b1v[j] = b1[n];
        w2v[j] = w2[n];
    }
#pragma unroll
    for (int i = 0; i < 4; ++i) {
#pragma unroll
        for (int r = 0; r < 4; ++r) {
            float s = 0.f;
#pragma unroll
            for (int j = 0; j < 8; ++j) {
                float h = acc[i][j][r] + b1v[j];
                s += fmaxf(h, 0.f) * w2v[j];
            }
            s += __shfl_xor(s, 1, 64);
            s += __shfl_xor(s, 2, 64);
            s += __shfl_xor(s, 4, 64);
            s += __shfl_xor(s, 8, 64);
            if (lr == 0) {
                int m = m0 + w_m + i * 16 + quad * 4 + r;   // C/D row = quad*4 + reg
                atomicAdd(&out[(m & (BATCH - 1)) * T_STEPS + (m >> 2)], s);  // -> [b][t]
            }
        }
    }
}

// ------------- finish: soft output (blocks 0..63) + serial LIF scan (block 64) -------------
// Scan is a 4096-step serial chain; loads are L2-latency-bound if issued in-chain.
// Fix: 16-step register prefetch ring (load chunk c+1 before processing chunk c;
// ~250 cyc of chain work hides the ~200 cyc L2 latency). x+bb2 / rl>0 computed off-chain.
__global__ void __launch_bounds__(256)
finish(const float* __restrict__ logits,
       const float* __restrict__ bb2p, const float* __restrict__ br2p,
       float* __restrict__ out)
{
    if (blockIdx.x < 64) {
        int i = blockIdx.x * 256 + threadIdx.x;
        out[i] = logits[i] + bb2p[0];                // soft = boundary logits [b][t] + bb2
        return;
    }
    int b = threadIdx.x;
    if (b >= BATCH) return;
    const float bb2 = bb2p[0];
    const float br2 = br2p[0];
    const float* xb = logits + b * T_STEPS;          // boundary logits, [b][t]
    const float* xr = logits + M_ROWS + b * T_STEPS; // reset logits
    float* hb = out + M_ROWS + b * T_STEPS;

    float4 cx[4], cr[4], nx[4] = {}, nr[4] = {};
#pragma unroll
    for (int q = 0; q < 4; ++q) {
        cx[q] = *(const float4*)(xb + q * 4);
        cr[q] = *(const float4*)(xr + q * 4);
    }

    float v = 0.f;
    for (int t0 = 0; t0 < T_STEPS; t0 += 16) {
        if (t0 + 16 < T_STEPS) {
#pragma unroll
            for (int q = 0; q < 4; ++q) {
                nx[q] = *(const float4*)(xb + t0 + 16 + q * 4);
                nr[q] = *(const float4*)(xr + t0 + 16 + q * 4);
            }
        }
#pragma unroll
        for (int q = 0; q < 4; ++q) {
            // off-chain precompute (same ops as before, just hoisted)
            float xs[4] = { cx[q].x + bb2, cx[q].y + bb2, cx[q].z + bb2, cx[q].w + bb2 };
            bool  rm[4] = { cr[q].x + br2 > 0.f, cr[q].y + br2 > 0.f,
                            cr[q].z + br2 > 0.f, cr[q].w + br2 > 0.f };
            float4 sv;
#pragma unroll
            for (int u = 0; u < 4; ++u) {
                v = v + (xs[u] - v) * 0.5f;          // bit-identical to reference step
                bool spike = (v >= 1.0f);
                ((float*)&sv)[u] = spike ? 1.0f : 0.0f;
                v = (spike || rm[u]) ? 0.f : v;
            }
            *(float4*)(hb + t0 + q * 4) = sv;
        }
#pragma unroll
        for (int q = 0; q < 4; ++q) { cx[q] = nx[q]; cr[q] = nr[q]; }
    }
}

extern "C" void kernel_launch(void* const* d_in, const int* in_sizes, int n_in,
                              void* d_out, int out_size, void* d_ws, size_t ws_size,
                              hipStream_t stream) {
    // dict order (confirmed): hidden, Wb1, bb1, Wb2, bb2, Wr1, br1, Wr2, br2
    const float* hidden = (const float*)d_in[0];   // [T,B,D] f32
    const float* Wb1    = (const float*)d_in[1];   // [D,H]
    const float* bb1    = (const float*)d_in[2];   // [H]
    const float* Wb2    = (const float*)d_in[3];   // [H,1]
    const float* bb2    = (const float*)d_in[4];   // [1]
    const float* Wr1    = (const float*)d_in[5];
    const float* br1    = (const float*)d_in[6];
    const float* Wr2    = (const float*)d_in[7];
    const float* br2    = (const float*)d_in[8];
    float* out = (float*)d_out;                    // f32: [soft B*T][hard B*T]

    // ws layout (96.13 MB): Xhi 32MB | Xlo 32MB | WThi 16MB | WTlo 16MB | logits 128KB
    unsigned short* Xhi  = (unsigned short*)d_ws;
    unsigned short* Xlo  = Xhi  + (size_t)M_ROWS * D_IN;
    unsigned short* WThi = Xlo  + (size_t)M_ROWS * D_IN;
    unsigned short* WTlo = WThi + (size_t)2 * H_DIM * D_IN;
    float* logits = (float*)(WTlo + (size_t)2 * H_DIM * D_IN);

    prep<<<dim3(6176), 256, 0, stream>>>(hidden, Wb1, Wr1, Xhi, Xlo, WThi, WTlo, logits);
    gemm_fused3<<<dim3(H_DIM / 256, M_ROWS / 128, 2), 256, 0, stream>>>(
        Xhi, Xlo, WThi, WTlo, bb1, br1, Wb2, Wr2, logits);
    finish<<<dim3(65), 256, 0, stream>>>(logits, bb2, br2, out);
}